// Round 1
// baseline (10625.647 us; speedup 1.0000x reference)
//
#include <hip/hip_runtime.h>
#include <cstdint>

#define T_DIM 2048
#define D_DIM 16
#define H_DIM 32

// ws float layout:
// [0,1024)    W1q   (row-major [k][j], k=0..31, j=0..31)
// [1024,1536) W2q   ([j][d], j=0..31, d=0..15)
// [1536,1568) b1
// [1568,1584) b2
// [1584,1616) inv_c
// [1616,1648) c_s
// [1648,1680) rho_s
// [1680,1712) L = 6*c_s

__global__ __launch_bounds__(256) void prep_kernel(
    const float* __restrict__ W1, const float* __restrict__ b1,
    const float* __restrict__ W2, const float* __restrict__ b2,
    const float* __restrict__ c,  const float* __restrict__ rho,
    float* __restrict__ wsp)
{
    __shared__ float red[256];
    const int t = threadIdx.x;

    // s1 = max(max|W1|, 1e-8) / 7
    float m = 0.0f;
    for (int i = t; i < 1024; i += 256) m = fmaxf(m, fabsf(W1[i]));
    red[t] = m;
    __syncthreads();
    for (int s = 128; s > 0; s >>= 1) {
        if (t < s) red[t] = fmaxf(red[t], red[t + s]);
        __syncthreads();
    }
    const float s1 = fmaxf(red[0], 1e-8f) / 7.0f;
    __syncthreads();

    // s2 = max(max|W2|, 1e-8) / 7
    m = 0.0f;
    for (int i = t; i < 512; i += 256) m = fmaxf(m, fabsf(W2[i]));
    red[t] = m;
    __syncthreads();
    for (int s = 128; s > 0; s >>= 1) {
        if (t < s) red[t] = fmaxf(red[t], red[t + s]);
        __syncthreads();
    }
    const float s2 = fmaxf(red[0], 1e-8f) / 7.0f;

    // W1q = q*s + (W - q*s), each op in fp32, no contraction across statements
    for (int i = t; i < 1024; i += 256) {
        const float w = W1[i];
        const float q = fminf(fmaxf(rintf(w / s1), -7.0f), 7.0f);
        const float qs = q * s1;
        const float resid = w - qs;
        wsp[i] = qs + resid;
    }
    for (int i = t; i < 512; i += 256) {
        const float w = W2[i];
        const float q = fminf(fmaxf(rintf(w / s2), -7.0f), 7.0f);
        const float qs = q * s2;
        const float resid = w - qs;
        wsp[1024 + i] = qs + resid;
    }
    if (t < 32) wsp[1536 + t] = b1[t];
    if (t < 16) wsp[1568 + t] = b2[t];
    if (t < 32) {
        const float cs = fmaxf(c[t], 0.1f);
        const float rs = fmaxf(rho[t], 0.0f);
        wsp[1584 + t] = 1.0f / cs;
        wsp[1616 + t] = cs;
        wsp[1648 + t] = rs;
        wsp[1680 + t] = 6.0f * cs;
    }
}

// one tree pair-op: cat[32] -> h = c19(cat@W1 + b1) -> o = h@W2 + b2
__device__ __forceinline__ void pair_op(
    const float* __restrict__ cat, float* __restrict__ o,
    const float* __restrict__ W1s, const float* __restrict__ W2s,
    const float* __restrict__ b1s, const float* __restrict__ b2s,
    const float* __restrict__ invcs, const float* __restrict__ css,
    const float* __restrict__ rhos, const float* __restrict__ Ls)
{
    float acc[32];
#pragma unroll
    for (int j = 0; j < 32; ++j) acc[j] = b1s[j];
#pragma unroll
    for (int k = 0; k < 32; ++k) {
        const float ck = cat[k];
#pragma unroll
        for (int j = 0; j < 32; ++j)
            acc[j] = fmaf(ck, W1s[k * 32 + j], acc[j]);
    }
    // c19 activation
#pragma unroll
    for (int j = 0; j < 32; ++j) {
        const float xv = acc[j];
        const float scaled = xv * invcs[j];
        const float nf = floorf(scaled);
        const float tt = scaled - nf;
        const float hh = tt * (1.0f - tt);
        const int ni = (int)nf;
        const float sgn = (ni & 1) ? -1.0f : 1.0f;
        float r = css[j] * (sgn * hh + rhos[j] * (hh * hh));
        const float Lj = Ls[j];
        r = (xv >= Lj) ? (xv - Lj) : r;
        r = (xv <= -Lj) ? (xv + Lj) : r;
        acc[j] = r;
    }
    float ov[16];
#pragma unroll
    for (int d = 0; d < 16; ++d) ov[d] = b2s[d];
#pragma unroll
    for (int j = 0; j < 32; ++j) {
        const float aj = acc[j];
#pragma unroll
        for (int d = 0; d < 16; ++d)
            ov[d] = fmaf(aj, W2s[j * 16 + d], ov[d]);
    }
#pragma unroll
    for (int d = 0; d < 16; ++d) o[d] = ov[d];
}

__device__ __forceinline__ void load_cat32(const float* __restrict__ src, float* cat)
{
#pragma unroll
    for (int v = 0; v < 8; ++v) {
        const float4 f = ((const float4*)src)[v];
        cat[4 * v + 0] = f.x;
        cat[4 * v + 1] = f.y;
        cat[4 * v + 2] = f.z;
        cat[4 * v + 3] = f.w;
    }
}

__global__ __launch_bounds__(256, 3) void tree_kernel(
    const float* __restrict__ x, const float* __restrict__ wsp,
    float* __restrict__ out)
{
    __shared__ float W1s[1024];
    __shared__ float W2s[512];
    __shared__ float b1s[32], b2s[16], invcs[32], css[32], rhos[32], Ls[32];
    __shared__ float nodes[16][512];   // feature-major: conflict-light

    const int t = threadIdx.x;
    const int n = blockIdx.x;

    for (int i = t; i < 1024; i += 256) W1s[i] = wsp[i];
    for (int i = t; i < 512; i += 256) W2s[i] = wsp[1024 + i];
    if (t < 32) {
        b1s[t]   = wsp[1536 + t];
        invcs[t] = wsp[1584 + t];
        css[t]   = wsp[1616 + t];
        rhos[t]  = wsp[1648 + t];
        Ls[t]    = wsp[1680 + t];
    }
    if (t < 16) b2s[t] = wsp[1568 + t];
    __syncthreads();

    const float* __restrict__ xrow = x + (size_t)n * (T_DIM * D_DIM);

    // head: levels 0-1 fully in registers; each lane folds 4 timesteps per u
#pragma unroll 1
    for (int u = 0; u < 2; ++u) {
        const int g = u * 256 + t;                    // L1 node index (0..511)
        const float* src = xrow + (size_t)g * 64;     // 4 timesteps * 16 floats
        float cat[32], oA[32], nv[16];
        load_cat32(src, cat);
        pair_op(cat, oA, W1s, W2s, b1s, b2s, invcs, css, rhos, Ls);
        load_cat32(src + 32, cat);
        pair_op(cat, oA + 16, W1s, W2s, b1s, b2s, invcs, css, rhos, Ls);
        pair_op(oA, nv, W1s, W2s, b1s, b2s, invcs, css, rhos, Ls);
#pragma unroll
        for (int d = 0; d < 16; ++d) nodes[d][g] = nv[d];
    }
    __syncthreads();

    // tail: levels with P = 256 .. 1 pairs
#pragma unroll 1
    for (int P = 256; P >= 1; P >>= 1) {
        float cat[32];
        const bool active = (t < P);
        if (active) {
#pragma unroll
            for (int d = 0; d < 16; ++d) {
                cat[d]      = nodes[d][2 * t];
                cat[16 + d] = nodes[d][2 * t + 1];
            }
        }
        __syncthreads();
        if (active) {
            float nv[16];
            pair_op(cat, nv, W1s, W2s, b1s, b2s, invcs, css, rhos, Ls);
            if (P > 1) {
#pragma unroll
                for (int d = 0; d < 16; ++d) nodes[d][t] = nv[d];
            } else {
#pragma unroll
                for (int d = 0; d < 16; ++d) out[(size_t)n * 16 + d] = nv[d];
            }
        }
        __syncthreads();
    }
}

extern "C" void kernel_launch(void* const* d_in, const int* in_sizes, int n_in,
                              void* d_out, int out_size, void* d_ws, size_t ws_size,
                              hipStream_t stream) {
    const float* x   = (const float*)d_in[0];
    const float* W1  = (const float*)d_in[1];
    const float* b1  = (const float*)d_in[2];
    const float* W2  = (const float*)d_in[3];
    const float* b2  = (const float*)d_in[4];
    const float* c   = (const float*)d_in[5];
    const float* rho = (const float*)d_in[6];
    float* out = (float*)d_out;
    float* wsp = (float*)d_ws;

    const int N = in_sizes[0] / (T_DIM * D_DIM);   // 4096

    prep_kernel<<<1, 256, 0, stream>>>(W1, b1, W2, b2, c, rho, wsp);
    tree_kernel<<<N, 256, 0, stream>>>(x, wsp, out);
}